// Round 1
// baseline (294.735 us; speedup 1.0000x reference)
//
#include <hip/hip_runtime.h>

// Problem constants (from reference)
#define HW    256   // input spatial
#define PH    64    // pooled H (HW/PATCH)
#define PW    64
#define CIN   32
#define NB    4
#define NNODE 4096  // PH*PW
#define EPS_W 1e-6f

// ---------------------------------------------------------------------------
// Kernel 1: per-patch channel-sum S[b, r, cc] = sum_c mean_{4x4}(x_feat)
//           and certainty XV[b, r, cc] = 1 - mean_{4x4}(x_var)
// grid: NB*PH blocks (one pooled row each), 256 threads = 4 waves.
// Wave w handles channels [8w, 8w+8); lane l owns pooled column l.
// Each load: lanes 0..63 read consecutive float4 -> 1 KiB coalesced.
// ---------------------------------------------------------------------------
__global__ __launch_bounds__(256) void pool_kernel(
    const float* __restrict__ x_feat, const float* __restrict__ x_var,
    float* __restrict__ S, float* __restrict__ XV) {
    const int blk  = blockIdx.x;        // b*PH + r
    const int b    = blk >> 6;
    const int r    = blk & 63;
    const int lane = threadIdx.x & 63;
    const int wave = threadIdx.x >> 6;

    __shared__ float red[256];

    float acc = 0.f;
    #pragma unroll
    for (int c = 0; c < 8; ++c) {
        const int ch = wave * 8 + c;
        const float4* p =
            (const float4*)(x_feat + (((size_t)(b * CIN + ch) * HW + r * 4) * HW)) + lane;
        #pragma unroll
        for (int pr = 0; pr < 4; ++pr) {
            float4 v = p[pr * (HW / 4)];
            acc += v.x + v.y + v.z + v.w;
        }
    }
    red[threadIdx.x] = acc;
    __syncthreads();

    if (wave == 0) {
        float s = red[lane] + red[lane + 64] + red[lane + 128] + red[lane + 192];
        S[(b << 12) + (r << 6) + lane] = s * (1.0f / 16.0f);
    } else if (wave == 1) {
        const float4* p = (const float4*)(x_var + ((size_t)b * HW + r * 4) * HW) + lane;
        float a = 0.f;
        #pragma unroll
        for (int pr = 0; pr < 4; ++pr) {
            float4 v = p[pr * (HW / 4)];
            a += v.x + v.y + v.z + v.w;
        }
        XV[(b << 12) + (r << 6) + lane] = 1.0f - a * (1.0f / 16.0f);
    }
}

// ---------------------------------------------------------------------------
// Kernel 2: nodes output. Raw reshape of broadcast channel-sum means
//   nodes_flat[b*131072 + g] = S[b, g & 4095].
// float4-vectorized: 32768 float4 per batch, S is 1024 float4 per batch.
// grid: 512 x 256 = 131072 threads (exact).
// ---------------------------------------------------------------------------
__global__ __launch_bounds__(256) void nodes_kernel(
    const float* __restrict__ S, float* __restrict__ out) {
    const int i = blockIdx.x * blockDim.x + threadIdx.x;  // float4 index
    const int b = i >> 15;
    const int g = i & 32767;
    float4 v = ((const float4*)S)[(b << 10) + (g & 1023)];
    ((float4*)out)[i] = v;
}

// ---------------------------------------------------------------------------
// Kernel 3: adjacency scatter. adj pre-zeroed by memset; write only the
// <= 4 nonzero entries per node: adj[b, nbr, pos] = xv[nbr]-xv[pos] if > EPS.
// (Reference's invalid-direction path adds 0.0 -> no store needed.)
// All (nbr,pos) pairs distinct across directions -> plain stores correct.
// grid: 64 x 256 = 16384 threads (exact).
// ---------------------------------------------------------------------------
__global__ __launch_bounds__(256) void scatter_kernel(
    const float* __restrict__ XV, float* __restrict__ adj) {
    const int i   = blockIdx.x * blockDim.x + threadIdx.x;  // b*4096 + pos
    const int b   = i >> 12;
    const int pos = i & 4095;
    const int r   = pos >> 6;
    const int c   = pos & 63;

    const float  self = XV[i];
    const float* xvb  = XV + (b << 12);
    float*       A    = adj + (size_t)b * NNODE * NNODE;

    if (r + 1 < PH) {  // dir (1,0): from = (r+1, c)
        float d = xvb[pos + 64] - self;
        if (d > EPS_W) A[(size_t)(pos + 64) * NNODE + pos] = d;
    }
    if (r - 1 >= 0) {  // dir (-1,0)
        float d = xvb[pos - 64] - self;
        if (d > EPS_W) A[(size_t)(pos - 64) * NNODE + pos] = d;
    }
    if (c + 1 < PW) {  // dir (0,1)
        float d = xvb[pos + 1] - self;
        if (d > EPS_W) A[(size_t)(pos + 1) * NNODE + pos] = d;
    }
    if (c - 1 >= 0) {  // dir (0,-1)
        float d = xvb[pos - 1] - self;
        if (d > EPS_W) A[(size_t)(pos - 1) * NNODE + pos] = d;
    }
}

extern "C" void kernel_launch(void* const* d_in, const int* in_sizes, int n_in,
                              void* d_out, int out_size, void* d_ws, size_t ws_size,
                              hipStream_t stream) {
    const float* x_feat = (const float*)d_in[0];  // (4,32,256,256) fp32
    const float* x_var  = (const float*)d_in[1];  // (4,1,256,256) fp32
    float* out = (float*)d_out;                   // nodes (524288) ++ adj (67108864)

    float* S  = (float*)d_ws;            // NB*NNODE floats
    float* XV = S + NB * NNODE;          // NB*NNODE floats  (total 128 KiB ws)

    // Zero entire output (adj must be zeros; nodes region overwritten below).
    hipMemsetAsync(d_out, 0, (size_t)out_size * sizeof(float), stream);

    pool_kernel<<<NB * PH, 256, 0, stream>>>(x_feat, x_var, S, XV);
    nodes_kernel<<<512, 256, 0, stream>>>(S, out);
    scatter_kernel<<<64, 256, 0, stream>>>(XV, out + (size_t)NB * CIN * NNODE);
}

// Round 3
// 284.439 us; speedup vs baseline: 1.0362x; 1.0362x over previous
//
#include <hip/hip_runtime.h>

// Problem constants (from reference)
#define HW    256   // input spatial
#define PH    64    // pooled H (HW/PATCH)
#define PW    64
#define CIN   32
#define NB    4
#define NNODE 4096  // PH*PW
#define EPS_W 1e-6f

typedef float f32x4 __attribute__((ext_vector_type(4)));

// ---------------------------------------------------------------------------
// Kernel 1: per-patch channel-sum S[b, r, cc] = sum_c mean_{4x4}(x_feat)
//           and certainty XV[b, r, cc] = 1 - mean_{4x4}(x_var)
// grid: NB*PH blocks (one pooled row each), 256 threads = 4 waves.
// Wave w handles channels [8w, 8w+8); lane l owns pooled column l.
// Each load: lanes 0..63 read consecutive float4 -> 1 KiB coalesced.
// ---------------------------------------------------------------------------
__global__ __launch_bounds__(256) void pool_kernel(
    const float* __restrict__ x_feat, const float* __restrict__ x_var,
    float* __restrict__ S, float* __restrict__ XV) {
    const int blk  = blockIdx.x;        // b*PH + r
    const int b    = blk >> 6;
    const int r    = blk & 63;
    const int lane = threadIdx.x & 63;
    const int wave = threadIdx.x >> 6;

    __shared__ float red[256];

    float acc = 0.f;
    #pragma unroll
    for (int c = 0; c < 8; ++c) {
        const int ch = wave * 8 + c;
        const float4* p =
            (const float4*)(x_feat + (((size_t)(b * CIN + ch) * HW + r * 4) * HW)) + lane;
        #pragma unroll
        for (int pr = 0; pr < 4; ++pr) {
            float4 v = p[pr * (HW / 4)];
            acc += v.x + v.y + v.z + v.w;
        }
    }
    red[threadIdx.x] = acc;
    __syncthreads();

    if (wave == 0) {
        float s = red[lane] + red[lane + 64] + red[lane + 128] + red[lane + 192];
        S[(b << 12) + (r << 6) + lane] = s * (1.0f / 16.0f);
    } else if (wave == 1) {
        const float4* p = (const float4*)(x_var + ((size_t)b * HW + r * 4) * HW) + lane;
        float a = 0.f;
        #pragma unroll
        for (int pr = 0; pr < 4; ++pr) {
            float4 v = p[pr * (HW / 4)];
            a += v.x + v.y + v.z + v.w;
        }
        XV[(b << 12) + (r << 6) + lane] = 1.0f - a * (1.0f / 16.0f);
    }
}

// ---------------------------------------------------------------------------
// Kernel 2: nodes output. Raw reshape of broadcast channel-sum means
//   nodes_flat[b*131072 + g] = S[b, g & 4095].
// float4-vectorized: 32768 float4 per batch, S is 1024 float4 per batch.
// grid: 512 x 256 = 131072 threads (exact).
// ---------------------------------------------------------------------------
__global__ __launch_bounds__(256) void nodes_kernel(
    const float* __restrict__ S, float* __restrict__ out) {
    const int i = blockIdx.x * blockDim.x + threadIdx.x;  // float4 index
    const int b = i >> 15;
    const int g = i & 32767;
    float4 v = ((const float4*)S)[(b << 10) + (g & 1023)];
    ((float4*)out)[i] = v;
}

// ---------------------------------------------------------------------------
// Kernel 3 (fused zero + values): one streaming pass writing all of adj.
// Row `from` of adj has <= 4 nonzero cols: from-64, from-1, from+1, from+64
// (with row-boundary validity for the +-1 cases), value xv[from]-xv[col] if
// > EPS. Everything else is 0. One float4 nontemporal store per thread:
// 16,777,216 float4 = 268 MB written exactly once. Slow path (xv loads,
// ~16 KB/batch, L1/L2-resident) taken by ~3% of threads.
// grid: 65536 x 256, 1:1 thread->float4 mapping.
// ---------------------------------------------------------------------------
__global__ __launch_bounds__(256) void adj_kernel(
    const float* __restrict__ XV, float* __restrict__ adj) {
    const int i    = blockIdx.x * blockDim.x + threadIdx.x;  // float4 index
    const int b    = i >> 22;          // 4096*1024 float4 per batch
    const int rem  = i & 4194303;
    const int from = rem >> 10;        // adj row
    const int c0   = (rem & 1023) << 2;  // first col of this float4

    f32x4 v = (f32x4)(0.f);

    // Possible nonzero cols lie in [from-64, from+64]; this float4 covers
    // [c0, c0+3]. Overlap iff c0 in [from-67, from+64].
    if (c0 >= from - 67 && c0 <= from + 64) {
        const float* xvb = XV + (b << 12);
        const float  xvf = xvb[from];
        #pragma unroll
        for (int j = 0; j < 4; ++j) {
            const int col = c0 + j;
            const int d   = from - col;
            const bool nb = (d == 64) | (d == -64) |
                            ((d == 1)  & ((from & 63) != 0)) |
                            ((d == -1) & ((from & 63) != 63));
            if (nb) {
                float diff = xvf - xvb[col];
                v[j] = diff > EPS_W ? diff : 0.f;
            }
        }
    }
    __builtin_nontemporal_store(v, (f32x4*)adj + i);
}

extern "C" void kernel_launch(void* const* d_in, const int* in_sizes, int n_in,
                              void* d_out, int out_size, void* d_ws, size_t ws_size,
                              hipStream_t stream) {
    const float* x_feat = (const float*)d_in[0];  // (4,32,256,256) fp32
    const float* x_var  = (const float*)d_in[1];  // (4,1,256,256) fp32
    float* out = (float*)d_out;                   // nodes (524288) ++ adj (67108864)

    float* S  = (float*)d_ws;            // NB*NNODE floats
    float* XV = S + NB * NNODE;          // NB*NNODE floats  (total 128 KiB ws)

    pool_kernel<<<NB * PH, 256, 0, stream>>>(x_feat, x_var, S, XV);
    nodes_kernel<<<512, 256, 0, stream>>>(S, out);
    adj_kernel<<<65536, 256, 0, stream>>>(XV, out + (size_t)NB * CIN * NNODE);
}